// Round 1
// baseline (981.149 us; speedup 1.0000x reference)
//
#include <hip/hip_runtime.h>
#include <hip/hip_bf16.h>
#include <stdint.h>

#define K_NB    50
#define DELTA   1e-3f
#define NKEYS   200000
#define BROWS   1024
#define HDIM    64
#define SDIM    256
#define ADIM    18
#define SAMPLE  2048
#define CAPMAX  4096

// out layout (floats): policy [0,18432) | value [18432,19456) | h [19456,84992)
#define OUT_VAL_OFF 18432
#define OUT_H_OFF   19456

// ---------- helpers: monotone float<->uint order map (valid for all floats) ----------
__device__ __forceinline__ unsigned ford(float f) {
    unsigned u = __float_as_uint(f);
    return (u & 0x80000000u) ? ~u : (u | 0x80000000u);
}
__device__ __forceinline__ float funord(unsigned u) {
    u = (u & 0x80000000u) ? (u & 0x7FFFFFFFu) : ~u;
    return __uint_as_float(u);
}

// ---------- K1: h = relu(x@W1+b1), hsq, policy, zero cnt ----------
__global__ __launch_bounds__(64) void k_mlp(
    const float* __restrict__ x, const float* __restrict__ W1,
    const float* __restrict__ b1, const float* __restrict__ Wp,
    const float* __restrict__ bp, float* __restrict__ out,
    float* __restrict__ ws_h, float* __restrict__ hsq,
    unsigned* __restrict__ cnt)
{
    const int b = blockIdx.x;
    const int j = threadIdx.x;
    const float* xr = x + b * SDIM;
    float a0 = 0.f, a1 = 0.f, a2 = 0.f, a3 = 0.f;
    #pragma unroll 8
    for (int s = 0; s < SDIM; s += 4) {
        a0 = fmaf(xr[s+0], W1[(s+0)*HDIM + j], a0);
        a1 = fmaf(xr[s+1], W1[(s+1)*HDIM + j], a1);
        a2 = fmaf(xr[s+2], W1[(s+2)*HDIM + j], a2);
        a3 = fmaf(xr[s+3], W1[(s+3)*HDIM + j], a3);
    }
    float h = (a0 + a1) + (a2 + a3) + b1[j];
    h = fmaxf(h, 0.f);
    ws_h[b*HDIM + j] = h;
    out[OUT_H_OFF + b*HDIM + j] = h;

    float sq = h * h;
    #pragma unroll
    for (int m = 32; m >= 1; m >>= 1) sq += __shfl_xor(sq, m, 64);
    if (j == 0) { hsq[b] = sq; cnt[b] = 0u; }

    __shared__ float hl[HDIM];
    hl[j] = h;
    __syncthreads();
    if (j < ADIM) {
        float p = bp[j];
        #pragma unroll 8
        for (int k = 0; k < HDIM; k++) p = fmaf(hl[k], Wp[k*ADIM + j], p);
        out[b*ADIM + j] = p;
    }
}

// ---------- K2: ksq[n] = ||key_n||^2 ----------
__global__ __launch_bounds__(256) void k_ksq(
    const float* __restrict__ keys, float* __restrict__ ksq)
{
    const int t = threadIdx.x;
    const int key = blockIdx.x * 16 + (t >> 4);
    const int l = t & 15;
    float4 v = *(const float4*)(keys + (size_t)key * HDIM + l * 4);
    float s = v.x*v.x + v.y*v.y + v.z*v.z + v.w*v.w;
    s += __shfl_xor(s, 1, 64);
    s += __shfl_xor(s, 2, 64);
    s += __shfl_xor(s, 4, 64);
    s += __shfl_xor(s, 8, 64);
    if (l == 0) ksq[key] = s;
}

// ---------- K3: per-row threshold = rank-th smallest distance among keys[0..2047] ----------
__global__ __launch_bounds__(256) void k_thresh(
    const float* __restrict__ keys, const float* __restrict__ ws_h,
    const float* __restrict__ hsq, const float* __restrict__ ksq,
    float* __restrict__ thr, int rank)
{
    __shared__ float hrow[4][HDIM];
    __shared__ float dbuf[4][SAMPLE];
    const int t = threadIdx.x;
    const int wv = t >> 6;      // wave = local row
    const int l = t & 63;
    const int row = blockIdx.x * 4 + wv;

    hrow[wv][l] = ws_h[row * HDIM + l];
    __syncthreads();
    const float hs = hsq[row];

    #pragma unroll 2
    for (int m = 0; m < SAMPLE / 64; m++) {
        const int k = l + 64 * m;
        const float* kr = keys + (size_t)k * HDIM;
        float acc = 0.f;
        #pragma unroll
        for (int d = 0; d < HDIM; d += 4) {
            float4 kv = *(const float4*)(kr + d);
            acc = fmaf(hrow[wv][d+0], kv.x, acc);
            acc = fmaf(hrow[wv][d+1], kv.y, acc);
            acc = fmaf(hrow[wv][d+2], kv.z, acc);
            acc = fmaf(hrow[wv][d+3], kv.w, acc);
        }
        dbuf[wv][k] = hs + ksq[k] - 2.f * acc;
    }
    __syncthreads();

    float tval = 0.f;
    for (int it = 0; it < rank; it++) {
        float best = __uint_as_float(0x7F800000);  // +inf
        int bslot = 0;
        #pragma unroll
        for (int m = 0; m < SAMPLE / 64; m++) {
            float v = dbuf[wv][l + 64 * m];
            if (v < best) { best = v; bslot = l + 64 * m; }
        }
        unsigned long long p = ((unsigned long long)ford(best) << 32) | (unsigned)bslot;
        #pragma unroll
        for (int m = 1; m < 64; m <<= 1) {
            unsigned long long q = __shfl_xor(p, m, 64);
            if (q < p) p = q;
        }
        if (l == 0) dbuf[wv][(int)(unsigned)p] = __uint_as_float(0x7F800000);
        if (it == rank - 1) tval = funord((unsigned)(p >> 32));
        __syncthreads();
    }
    if (l == 0) thr[row] = tval;
}

// ---------- K4: main distance GEMM + threshold filter ----------
#define TBROWS 128
#define TBKEYS 64
#define CHUNK  1600
#define ITERS  (CHUNK / TBKEYS)   // 25

__global__ __launch_bounds__(256) void k_dist(
    const float* __restrict__ keys, const float* __restrict__ ws_h,
    const float* __restrict__ hsq, const float* __restrict__ ksq,
    const float* __restrict__ thr, unsigned* __restrict__ cnt,
    float* __restrict__ cand_d, int* __restrict__ cand_i, int cap)
{
    __shared__ float hT[HDIM][132];   // [dim][row], padded: conflict-free reads
    __shared__ float kT[HDIM][68];    // [dim][key], padded: 2-way (free) reads

    const int t  = threadIdx.x;
    const int rg = t >> 4;            // 0..15 -> 8 rows each
    const int kg = t & 15;            // 0..15 -> 4 keys each
    const int row0 = blockIdx.y * TBROWS;
    const int n0   = blockIdx.x * CHUNK;

    // stage hT (transposed), one-time
    #pragma unroll
    for (int p = 0; p < 8; p++) {
        int s = t + 256 * p;          // 0..2047 float4 slots
        int r = s >> 4;
        int d4 = (s & 15) * 4;
        float4 v = *(const float4*)(ws_h + (size_t)(row0 + r) * HDIM + d4);
        hT[d4+0][r] = v.x; hT[d4+1][r] = v.y; hT[d4+2][r] = v.z; hT[d4+3][r] = v.w;
    }

    float hsq_r[8], thr_r[8];
    #pragma unroll
    for (int i = 0; i < 8; i++) {
        int r = row0 + rg * 8 + i;
        hsq_r[i] = hsq[r];
        thr_r[i] = thr[r];
    }

    // prefetch iter 0 key tile into registers
    float4 st[4];
    #pragma unroll
    for (int p = 0; p < 4; p++) {
        int s = t + 256 * p;          // 0..1023 float4 slots (64 keys x 16)
        st[p] = *(const float4*)(keys + (size_t)(n0 + (s >> 4)) * HDIM + (s & 15) * 4);
    }
    __syncthreads();                  // hT ready

    for (int it = 0; it < ITERS; it++) {
        // write staged key tile (transposed)
        #pragma unroll
        for (int p = 0; p < 4; p++) {
            int s = t + 256 * p;
            int k = s >> 4;
            int d4 = (s & 15) * 4;
            kT[d4+0][k] = st[p].x; kT[d4+1][k] = st[p].y;
            kT[d4+2][k] = st[p].z; kT[d4+3][k] = st[p].w;
        }
        // prefetch next tile
        if (it + 1 < ITERS) {
            int nb = n0 + (it + 1) * TBKEYS;
            #pragma unroll
            for (int p = 0; p < 4; p++) {
                int s = t + 256 * p;
                st[p] = *(const float4*)(keys + (size_t)(nb + (s >> 4)) * HDIM + (s & 15) * 4);
            }
        }
        __syncthreads();              // kT ready

        const int nbase = n0 + it * TBKEYS;
        float4 ksq4 = *(const float4*)(ksq + nbase + kg * 4);

        float acc[8][4] = {};
        #pragma unroll 8
        for (int d = 0; d < HDIM; d++) {
            float4 k4 = *(const float4*)&kT[d][kg * 4];
            float4 h0 = *(const float4*)&hT[d][rg * 8];
            float4 h1 = *(const float4*)&hT[d][rg * 8 + 4];
            float hv[8] = {h0.x,h0.y,h0.z,h0.w,h1.x,h1.y,h1.z,h1.w};
            float kv[4] = {k4.x,k4.y,k4.z,k4.w};
            #pragma unroll
            for (int i = 0; i < 8; i++)
                #pragma unroll
                for (int j = 0; j < 4; j++)
                    acc[i][j] = fmaf(hv[i], kv[j], acc[i][j]);
        }

        // epilogue: d = hsq + ksq - 2*dot; filter by threshold
        #pragma unroll
        for (int i = 0; i < 8; i++) {
            const float hs = hsq_r[i], tr = thr_r[i];
            const int r = row0 + rg * 8 + i;
            float ksv[4] = {ksq4.x, ksq4.y, ksq4.z, ksq4.w};
            #pragma unroll
            for (int j = 0; j < 4; j++) {
                float dd = hs + ksv[j] - 2.f * acc[i][j];
                if (dd < tr) {
                    unsigned pos = atomicAdd(&cnt[r], 1u);
                    if (pos < (unsigned)cap) {
                        cand_d[(size_t)r * cap + pos] = dd;
                        cand_i[(size_t)r * cap + pos] = nbase + kg * 4 + j;
                    }
                }
            }
        }
        __syncthreads();              // kT consumed
    }
}

// ---------- K5: exact top-50 over candidates + weighted value ----------
__global__ __launch_bounds__(256) void k_merge(
    const float* __restrict__ cand_d, const int* __restrict__ cand_i,
    const unsigned* __restrict__ cnt, const float* __restrict__ vals,
    float* __restrict__ out_val, int cap)
{
    __shared__ float ds[CAPMAX];
    __shared__ int   is_[CAPMAX];
    __shared__ unsigned long long wred[4];
    __shared__ float win_d[K_NB];
    __shared__ int   win_i[K_NB];

    const int r = blockIdx.x;
    const int t = threadIdx.x;
    const int c = (int)min(cnt[r], (unsigned)cap);

    for (int s = t; s < c; s += 256) {
        ds[s]  = cand_d[(size_t)r * cap + s];
        is_[s] = cand_i[(size_t)r * cap + s];
    }
    __syncthreads();

    const int kk = (c < K_NB) ? c : K_NB;
    for (int e = 0; e < kk; e++) {
        unsigned long long best = ~0ull;
        int bslot = -1;
        for (int s = t; s < c; s += 256) {
            unsigned long long p = ((unsigned long long)ford(ds[s]) << 32) | (unsigned)is_[s];
            if (p < best) { best = p; bslot = s; }
        }
        unsigned long long bw = best;
        #pragma unroll
        for (int m = 1; m < 64; m <<= 1) {
            unsigned long long q = __shfl_xor(bw, m, 64);
            if (q < bw) bw = q;
        }
        if ((t & 63) == 0) wred[t >> 6] = bw;
        __syncthreads();
        unsigned long long g = wred[0];
        if (wred[1] < g) g = wred[1];
        if (wred[2] < g) g = wred[2];
        if (wred[3] < g) g = wred[3];
        if (best == g && bslot >= 0) ds[bslot] = __uint_as_float(0x7F800000);  // remove winner
        if (t == 0) {
            win_d[e] = funord((unsigned)(g >> 32));
            win_i[e] = (int)(unsigned)(g & 0xFFFFFFFFull);
        }
        __syncthreads();
    }

    float wsum = 0.f, wvsum = 0.f;
    if (t < kk) {
        float dd = fmaxf(win_d[t], 0.f);
        float w = 1.f / (dd + DELTA);
        wsum = w;
        wvsum = w * vals[win_i[t]];
    }
    if (t < 64) {
        #pragma unroll
        for (int m = 1; m < 64; m <<= 1) {
            wsum  += __shfl_xor(wsum, m, 64);
            wvsum += __shfl_xor(wvsum, m, 64);
        }
        if (t == 0) out_val[r] = (kk > 0) ? (wvsum / wsum) : 0.f;
    }
}

// ---------- launch ----------
extern "C" void kernel_launch(void* const* d_in, const int* in_sizes, int n_in,
                              void* d_out, int out_size, void* d_ws, size_t ws_size,
                              hipStream_t stream)
{
    const float* x    = (const float*)d_in[0];
    const float* W1   = (const float*)d_in[1];
    const float* b1   = (const float*)d_in[2];
    const float* Wp   = (const float*)d_in[3];
    const float* bp   = (const float*)d_in[4];
    const float* keys = (const float*)d_in[5];
    const float* vals = (const float*)d_in[6];
    float* out = (float*)d_out;
    float* ws  = (float*)d_ws;

    // ws layout (float elements)
    float*    ws_h  = ws;                         // 65536
    float*    hsq   = ws + 65536;                 // 1024
    float*    ksq   = ws + 66560;                 // 200000
    float*    thr   = ws + 266560;                // 1024
    unsigned* cnt   = (unsigned*)(ws + 267584);   // 1024
    float*    cand_d = ws + 268608;

    // adaptive candidate cap (need ~35 MB for cap=4096)
    long avail_elems = (long)(ws_size / 4) - 268608;
    long capl = avail_elems / (2 * 1024);
    int cap = (int)capl;
    if (cap > CAPMAX) cap = CAPMAX;
    if (cap < 256) cap = 256;
    int* cand_i = (int*)(cand_d + (size_t)1024 * cap);

    int rank = cap / 340;               // keep expected count ~cap/3.5
    if (rank > 12) rank = 12;
    if (rank < 6)  rank = 6;

    k_mlp<<<BROWS, 64, 0, stream>>>(x, W1, b1, Wp, bp, out, ws_h, hsq, cnt);
    k_ksq<<<NKEYS / 16, 256, 0, stream>>>(keys, ksq);
    k_thresh<<<BROWS / 4, 256, 0, stream>>>(keys, ws_h, hsq, ksq, thr, rank);
    dim3 gdist(NKEYS / CHUNK, BROWS / TBROWS);     // (125, 8)
    k_dist<<<gdist, 256, 0, stream>>>(keys, ws_h, hsq, ksq, thr, cnt, cand_d, cand_i, cap);
    k_merge<<<BROWS, 256, 0, stream>>>(cand_d, cand_i, cnt, vals, out + OUT_VAL_OFF, cap);
}

// Round 2
// 882.416 us; speedup vs baseline: 1.1119x; 1.1119x over previous
//
#include <hip/hip_runtime.h>
#include <hip/hip_bf16.h>
#include <stdint.h>

#define K_NB    50
#define DELTA   1e-3f
#define NKEYS   200000
#define BROWS   1024
#define HDIM    64
#define SDIM    256
#define ADIM    18
#define SAMPLE  2048
#define CAPMAX  4096
#define NS      56          // pre-selection width in merge (exact top-50 subset)
#define NTILES  1563        // ceil(200000/128)

// out layout (floats): policy [0,18432) | value [18432,19456) | h [19456,84992)
#define OUT_VAL_OFF 18432
#define OUT_H_OFF   19456

typedef __attribute__((ext_vector_type(8))) short short8;
typedef __attribute__((ext_vector_type(4))) float f32x4;

// monotone float->uint order map
__device__ __forceinline__ unsigned ford(float f) {
    unsigned u = __float_as_uint(f);
    return (u & 0x80000000u) ? ~u : (u | 0x80000000u);
}
__device__ __forceinline__ float funord(unsigned u) {
    u = (u & 0x80000000u) ? (u & 0x7FFFFFFFu) : ~u;
    return __uint_as_float(u);
}

// RNE float -> bf16 bits
__device__ __forceinline__ unsigned short bf16_rne(float f) {
    unsigned u = __float_as_uint(f);
    unsigned r = u + 0x7FFFu + ((u >> 16) & 1u);
    return (unsigned short)(r >> 16);
}
__device__ __forceinline__ float bf16_tof(unsigned short b) {
    return __uint_as_float(((unsigned)b) << 16);
}

// ---------- K1: h = relu(x@W1+b1), hsq, policy, A2 (bf16 hi/lo), zero cnt ----------
__global__ __launch_bounds__(64) void k_mlp(
    const float* __restrict__ x, const float* __restrict__ W1,
    const float* __restrict__ b1, const float* __restrict__ Wp,
    const float* __restrict__ bp, float* __restrict__ out,
    float* __restrict__ ws_h, float* __restrict__ hsq,
    unsigned* __restrict__ cnt, unsigned short* __restrict__ a2)
{
    const int b = blockIdx.x;
    const int j = threadIdx.x;
    const float* xr = x + b * SDIM;
    float a0 = 0.f, a1 = 0.f, a2r = 0.f, a3 = 0.f;
    #pragma unroll 8
    for (int s = 0; s < SDIM; s += 4) {
        a0  = fmaf(xr[s+0], W1[(s+0)*HDIM + j], a0);
        a1  = fmaf(xr[s+1], W1[(s+1)*HDIM + j], a1);
        a2r = fmaf(xr[s+2], W1[(s+2)*HDIM + j], a2r);
        a3  = fmaf(xr[s+3], W1[(s+3)*HDIM + j], a3);
    }
    float h = (a0 + a1) + (a2r + a3) + b1[j];
    h = fmaxf(h, 0.f);
    ws_h[b*HDIM + j] = h;
    out[OUT_H_OFF + b*HDIM + j] = h;

    // bf16 hi/lo split for MFMA A-matrix: layout [row][hi(64) | lo(64)]
    unsigned short hi = bf16_rne(h);
    float lof = h - bf16_tof(hi);
    unsigned short lo = bf16_rne(lof);
    a2[b*128 + j]      = hi;
    a2[b*128 + 64 + j] = lo;

    float sq = h * h;
    #pragma unroll
    for (int m = 32; m >= 1; m >>= 1) sq += __shfl_xor(sq, m, 64);
    if (j == 0) { hsq[b] = sq; cnt[b] = 0u; }

    __shared__ float hl[HDIM];
    hl[j] = h;
    __syncthreads();
    if (j < ADIM) {
        float p = bp[j];
        #pragma unroll 8
        for (int k = 0; k < HDIM; k++) p = fmaf(hl[k], Wp[k*ADIM + j], p);
        out[b*ADIM + j] = p;
    }
}

// ---------- K2: ksq[n] = ||key_n||^2 ----------
__global__ __launch_bounds__(256) void k_ksq(
    const float* __restrict__ keys, float* __restrict__ ksq)
{
    const int t = threadIdx.x;
    const int key = blockIdx.x * 16 + (t >> 4);
    const int l = t & 15;
    float4 v = *(const float4*)(keys + (size_t)key * HDIM + l * 4);
    float s = v.x*v.x + v.y*v.y + v.z*v.z + v.w*v.w;
    s += __shfl_xor(s, 1, 64);
    s += __shfl_xor(s, 2, 64);
    s += __shfl_xor(s, 4, 64);
    s += __shfl_xor(s, 8, 64);
    if (l == 0) ksq[key] = s;
}

// ---------- K3: per-row threshold = rank-th smallest among keys[0..2047] (exact fp32) ----------
__global__ __launch_bounds__(256) void k_thresh(
    const float* __restrict__ keys, const float* __restrict__ ws_h,
    const float* __restrict__ hsq, const float* __restrict__ ksq,
    float* __restrict__ thr, int rank)
{
    __shared__ float hrow[4][HDIM];
    __shared__ float dbuf[4][SAMPLE];
    const int t = threadIdx.x;
    const int wv = t >> 6;
    const int l = t & 63;
    const int row = blockIdx.x * 4 + wv;

    hrow[wv][l] = ws_h[row * HDIM + l];
    __syncthreads();
    const float hs = hsq[row];

    #pragma unroll 2
    for (int m = 0; m < SAMPLE / 64; m++) {
        const int k = l + 64 * m;
        const float* kr = keys + (size_t)k * HDIM;
        float acc = 0.f;
        #pragma unroll
        for (int d = 0; d < HDIM; d += 4) {
            float4 kv = *(const float4*)(kr + d);
            acc = fmaf(hrow[wv][d+0], kv.x, acc);
            acc = fmaf(hrow[wv][d+1], kv.y, acc);
            acc = fmaf(hrow[wv][d+2], kv.z, acc);
            acc = fmaf(hrow[wv][d+3], kv.w, acc);
        }
        dbuf[wv][k] = hs + ksq[k] - 2.f * acc;
    }
    __syncthreads();

    float tval = 0.f;
    for (int it = 0; it < rank; it++) {
        float best = __uint_as_float(0x7F800000);
        int bslot = 0;
        #pragma unroll
        for (int m = 0; m < SAMPLE / 64; m++) {
            float v = dbuf[wv][l + 64 * m];
            if (v < best) { best = v; bslot = l + 64 * m; }
        }
        unsigned long long p = ((unsigned long long)ford(best) << 32) | (unsigned)bslot;
        #pragma unroll
        for (int m = 1; m < 64; m <<= 1) {
            unsigned long long q = __shfl_xor(p, m, 64);
            if (q < p) p = q;
        }
        if (l == 0) dbuf[wv][(int)(unsigned)p] = __uint_as_float(0x7F800000);
        if (it == rank - 1) tval = funord((unsigned)(p >> 32));
        __syncthreads();
    }
    if (l == 0) thr[row] = tval;
}

// ---------- K4: MFMA split-bf16 distance GEMM + threshold filter ----------
// Tile 128 rows x 128 keys, 4 waves in 2x2, each wave 64x64 (mf=4, nf=4).
// K = 192 logical via segments; only 4 distinct A-frags (hi0,hi1,lo0,lo1) and
// 4 distinct B-frags per column block. LDS B-tile [16 granules][128 keys].
__global__ __launch_bounds__(256, 2) void k_dist(
    const float* __restrict__ keys, const unsigned short* __restrict__ a2,
    const float* __restrict__ hsq, const float* __restrict__ ksq,
    const float* __restrict__ thr, unsigned* __restrict__ cnt,
    float* __restrict__ cand_d, int* __restrict__ cand_i, int cap)
{
    __shared__ short8 Bl[16][128];   // [k8 granule][key] : 32768 B

    const int t    = threadIdx.x;
    const int w    = t >> 6;
    const int lane = t & 63;
    const int wr0  = (w >> 1) * 64;      // wave row offset in tile
    const int wc0  = (w & 1) * 64;       // wave col offset in tile
    const int l15  = lane & 15;
    const int l4   = lane >> 4;          // 0..3
    const int row0 = blockIdx.y * 128;

    // A fragments: a[mf][at], at in {hi0,hi1,lo0,lo1} = elem offsets {0,32,64,96}
    short8 a[4][4];
    #pragma unroll
    for (int mf = 0; mf < 4; mf++) {
        int row = row0 + wr0 + mf * 16 + l15;
        #pragma unroll
        for (int at = 0; at < 4; at++)
            a[mf][at] = *(const short8*)(a2 + (size_t)row * 128 + at * 32 + l4 * 8);
    }

    // per-lane filter limits: s < (thr - hsq)/2  where s = ksq/2 - dot
    float lim[4][4];
    #pragma unroll
    for (int mf = 0; mf < 4; mf++)
        #pragma unroll
        for (int rg = 0; rg < 4; rg++) {
            int r = row0 + wr0 + mf * 16 + l4 * 4 + rg;
            lim[mf][rg] = (thr[r] - hsq[r]) * 0.5f;
        }

    // staging role: key = t>>1 (0..127), part = t&1 (dims part*32..+31)
    const int skey  = t >> 1;
    const int spart = t & 1;

    // prologue: load tile 0
    float4 f[8];
    {
        int nt = blockIdx.x;
        int kg = nt * 128 + skey;
        if (nt < NTILES && kg < NKEYS) {
            const float4* kp = (const float4*)(keys + (size_t)kg * HDIM + spart * 32);
            #pragma unroll
            for (int i = 0; i < 8; i++) f[i] = kp[i];
        } else {
            #pragma unroll
            for (int i = 0; i < 8; i++) f[i] = make_float4(0.f,0.f,0.f,0.f);
        }
    }

    for (int j = 0; j < 13; j++) {
        const int cur = blockIdx.x + j * 128;
        if (cur >= NTILES) break;                    // uniform per block

        // convert staged floats -> hi/lo bf16 packed
        short8 Hh[4], Ll[4];
        #pragma unroll
        for (int i = 0; i < 4; i++) {
            float fv[8] = { f[2*i].x, f[2*i].y, f[2*i].z, f[2*i].w,
                            f[2*i+1].x, f[2*i+1].y, f[2*i+1].z, f[2*i+1].w };
            #pragma unroll
            for (int q = 0; q < 8; q++) {
                unsigned short hb = bf16_rne(fv[q]);
                float lof = fv[q] - bf16_tof(hb);
                Hh[i][q] = (short)hb;
                Ll[i][q] = (short)bf16_rne(lof);
            }
        }

        // issue next-tile loads early (hidden under barriers+MFMA)
        {
            int nxt = cur + 128;
            int kg = nxt * 128 + skey;
            if (nxt < NTILES && kg < NKEYS) {
                const float4* kp = (const float4*)(keys + (size_t)kg * HDIM + spart * 32);
                #pragma unroll
                for (int i = 0; i < 8; i++) f[i] = kp[i];
            } else if (nxt < NTILES) {
                #pragma unroll
                for (int i = 0; i < 8; i++) f[i] = make_float4(0.f,0.f,0.f,0.f);
            }
        }

        __syncthreads();             // previous tile's B reads complete
        #pragma unroll
        for (int i = 0; i < 4; i++) {
            Bl[spart*4 + i][skey]     = Hh[i];   // hi granules 0..7
            Bl[8 + spart*4 + i][skey] = Ll[i];   // lo granules 8..15
        }
        __syncthreads();             // B tile ready

        // ksq/2 per nf column (guarded)
        float kh[4];
        #pragma unroll
        for (int nf = 0; nf < 4; nf++) {
            int col = cur * 128 + wc0 + nf * 16 + l15;
            kh[nf] = (col < NKEYS) ? 0.5f * ksq[col] : 3.0e37f;
        }

        f32x4 acc[4][4];
        #pragma unroll
        for (int mf = 0; mf < 4; mf++)
            #pragma unroll
            for (int nf = 0; nf < 4; nf++)
                acc[mf][nf] = (f32x4){0.f,0.f,0.f,0.f};

        // bt0: a{hi0,lo0}; bt1: a{hi1,lo1}; bt2: a{hi0}; bt3: a{hi1}
        #pragma unroll
        for (int bt = 0; bt < 4; bt++) {
            short8 bf[4];
            #pragma unroll
            for (int nf = 0; nf < 4; nf++)
                bf[nf] = Bl[bt*4 + l4][wc0 + nf*16 + l15];

            const int at0 = (bt < 2) ? bt : (bt - 2);    // hi0/hi1
            #pragma unroll
            for (int mf = 0; mf < 4; mf++)
                #pragma unroll
                for (int nf = 0; nf < 4; nf++)
                    acc[mf][nf] = __builtin_amdgcn_mfma_f32_16x16x32_bf16(
                        a[mf][at0], bf[nf], acc[mf][nf], 0, 0, 0);
            if (bt < 2) {                                 // paired lo
                const int at1 = bt + 2;                   // lo0/lo1
                #pragma unroll
                for (int mf = 0; mf < 4; mf++)
                    #pragma unroll
                    for (int nf = 0; nf < 4; nf++)
                        acc[mf][nf] = __builtin_amdgcn_mfma_f32_16x16x32_bf16(
                            a[mf][at1], bf[nf], acc[mf][nf], 0, 0, 0);
            }
        }

        // epilogue: s = ksq/2 - dot; store candidate iff s < lim  (d = hsq + 2s)
        #pragma unroll
        for (int mf = 0; mf < 4; mf++)
            #pragma unroll
            for (int nf = 0; nf < 4; nf++)
                #pragma unroll
                for (int rg = 0; rg < 4; rg++) {
                    float s = kh[nf] - acc[mf][nf][rg];
                    if (s < lim[mf][rg]) {
                        int row = row0 + wr0 + mf*16 + l4*4 + rg;
                        int col = cur*128 + wc0 + nf*16 + l15;
                        unsigned pos = atomicAdd(&cnt[row], 1u);
                        if (pos < (unsigned)cap) {
                            cand_d[(size_t)row * cap + pos] = s;
                            cand_i[(size_t)row * cap + pos] = col;
                        }
                    }
                }
    }
}

// ---------- K5: approx top-NS -> exact fp32 recompute -> exact top-50 + value ----------
__global__ __launch_bounds__(256) void k_merge(
    const float* __restrict__ cand_d, const int* __restrict__ cand_i,
    const unsigned* __restrict__ cnt, const float* __restrict__ vals,
    const float* __restrict__ keys, const float* __restrict__ ws_h,
    const float* __restrict__ hsq, const float* __restrict__ ksq,
    float* __restrict__ out_val, int cap)
{
    __shared__ unsigned long long wred2[4];
    __shared__ unsigned long long win[NS];
    __shared__ float hrow_s[HDIM];
    __shared__ float dex[NS];

    const int r = blockIdx.x;
    const int t = threadIdx.x;
    const int c = (int)min(cnt[r], (unsigned)cap);

    if (t < HDIM) hrow_s[t] = ws_h[(size_t)r * HDIM + t];

    // register-resident candidate pairs
    unsigned long long v[16];
    #pragma unroll
    for (int i = 0; i < 16; i++) {
        int s = t + 256 * i;
        v[i] = ~0ull;
        if (s < c)
            v[i] = ((unsigned long long)ford(cand_d[(size_t)r * cap + s]) << 32)
                 | (unsigned)cand_i[(size_t)r * cap + s];
    }

    // extract NS smallest (by approx score, idx tiebreak)
    for (int e = 0; e < NS; e++) {
        unsigned long long m = v[0];
        #pragma unroll
        for (int i = 1; i < 16; i++) m = (v[i] < m) ? v[i] : m;
        unsigned long long wm = m;
        #pragma unroll
        for (int mm = 1; mm < 64; mm <<= 1) {
            unsigned long long o = __shfl_xor(wm, mm, 64);
            wm = (o < wm) ? o : wm;
        }
        if ((t & 63) == 0) wred2[t >> 6] = wm;
        __syncthreads();
        unsigned long long g = wred2[0];
        if (wred2[1] < g) g = wred2[1];
        if (wred2[2] < g) g = wred2[2];
        if (wred2[3] < g) g = wred2[3];
        if (m == g && g != ~0ull) {
            #pragma unroll
            for (int i = 0; i < 16; i++) if (v[i] == g) v[i] = ~0ull;
        }
        if (t == 0) win[e] = g;
        __syncthreads();
    }

    // exact fp32 distance for the NS winners
    if (t < NS) {
        unsigned long long g = win[t];
        float dv = 3.0e38f;
        if (g != ~0ull) {
            int idx = (int)(unsigned)g;
            const float4* kp = (const float4*)(keys + (size_t)idx * HDIM);
            float acc = 0.f;
            #pragma unroll
            for (int q = 0; q < 16; q++) {
                float4 kv = kp[q];
                acc = fmaf(hrow_s[4*q+0], kv.x, acc);
                acc = fmaf(hrow_s[4*q+1], kv.y, acc);
                acc = fmaf(hrow_s[4*q+2], kv.z, acc);
                acc = fmaf(hrow_s[4*q+3], kv.w, acc);
            }
            dv = fmaxf(hsq[r] + ksq[idx] - 2.f * acc, 0.f);
        }
        dex[t] = dv;
    }
    __syncthreads();

    // exact top-50 by rank, weighted sum (wave 0)
    if (t < 64) {
        float dv = (t < NS) ? dex[t] : 3.0e38f;
        unsigned idx = (t < NS) ? (unsigned)win[t] : 0xFFFFFFFFu;
        unsigned long long me = ((unsigned long long)ford(dv) << 32) | idx;
        int rank = 0;
        for (int j2 = 0; j2 < NS; j2++) {
            unsigned long long o = __shfl(me, j2, 64);
            rank += (o < me) ? 1 : 0;
        }
        float wsum = 0.f, wv = 0.f;
        if (rank < K_NB && dv < 1.0e38f) {
            float wgt = 1.f / (dv + DELTA);
            wsum = wgt;
            wv = wgt * vals[idx];
        }
        #pragma unroll
        for (int m = 1; m < 64; m <<= 1) {
            wsum += __shfl_xor(wsum, m, 64);
            wv   += __shfl_xor(wv,   m, 64);
        }
        if (t == 0) out_val[r] = wv / wsum;
    }
}

// ---------- launch ----------
extern "C" void kernel_launch(void* const* d_in, const int* in_sizes, int n_in,
                              void* d_out, int out_size, void* d_ws, size_t ws_size,
                              hipStream_t stream)
{
    const float* x    = (const float*)d_in[0];
    const float* W1   = (const float*)d_in[1];
    const float* b1   = (const float*)d_in[2];
    const float* Wp   = (const float*)d_in[3];
    const float* bp   = (const float*)d_in[4];
    const float* keys = (const float*)d_in[5];
    const float* vals = (const float*)d_in[6];
    float* out = (float*)d_out;
    float* ws  = (float*)d_ws;

    // ws layout (float units)
    float*          ws_h = ws;                        // 65536
    float*          hsq  = ws + 65536;                // 1024
    float*          ksq  = ws + 66560;                // 200000
    float*          thr  = ws + 266560;               // 1024
    unsigned*       cnt  = (unsigned*)(ws + 267584);  // 1024
    unsigned short* a2   = (unsigned short*)(ws + 268608);  // 1024*128 ushort = 65536 floats
    float*          cand_d = ws + 334144;

    long avail_elems = (long)(ws_size / 4) - 334144;
    long capl = avail_elems / (2 * 1024);
    int cap = (int)capl;
    if (cap > CAPMAX) cap = CAPMAX;
    if (cap < 256) cap = 256;
    int* cand_i = (int*)(cand_d + (size_t)1024 * cap);

    int rank = cap / 340;
    if (rank > 12) rank = 12;
    if (rank < 6)  rank = 6;

    k_mlp<<<BROWS, 64, 0, stream>>>(x, W1, b1, Wp, bp, out, ws_h, hsq, cnt, a2);
    k_ksq<<<NKEYS / 16, 256, 0, stream>>>(keys, ksq);
    k_thresh<<<BROWS / 4, 256, 0, stream>>>(keys, ws_h, hsq, ksq, thr, rank);
    dim3 gdist(128, 8);
    k_dist<<<gdist, 256, 0, stream>>>(keys, a2, hsq, ksq, thr, cnt, cand_d, cand_i, cap);
    k_merge<<<BROWS, 256, 0, stream>>>(cand_d, cand_i, cnt, vals, keys, ws_h, hsq, ksq,
                                       out + OUT_VAL_OFF, cap);
}

// Round 3
// 695.712 us; speedup vs baseline: 1.4103x; 1.2684x over previous
//
#include <hip/hip_runtime.h>
#include <hip/hip_bf16.h>
#include <stdint.h>

#define K_NB    50
#define DELTA   1e-3f
#define NKEYS   200000
#define BROWS   1024
#define HDIM    64
#define SDIM    256
#define ADIM    18
#define SAMPLE  4096
#define RANKSEL 24
#define NS      56
#define NTILES  1563        // ceil(200000/128)
#define XB      64          // x-blocks in k_dist
#define JMAX    25          // ceil(NTILES/XB)

// out layout (floats): policy [0,18432) | value [18432,19456) | h [19456,84992)
#define OUT_VAL_OFF 18432
#define OUT_H_OFF   19456

typedef __attribute__((ext_vector_type(8))) short short8;
typedef __attribute__((ext_vector_type(4))) float f32x4;
typedef unsigned long long ull;

// monotone float->uint order map
__device__ __forceinline__ unsigned ford(float f) {
    unsigned u = __float_as_uint(f);
    return (u & 0x80000000u) ? ~u : (u | 0x80000000u);
}
__device__ __forceinline__ float funord(unsigned u) {
    u = (u & 0x80000000u) ? (u & 0x7FFFFFFFu) : ~u;
    return __uint_as_float(u);
}
__device__ __forceinline__ unsigned short bf16_rne(float f) {
    unsigned u = __float_as_uint(f);
    unsigned r = u + 0x7FFFu + ((u >> 16) & 1u);
    return (unsigned short)(r >> 16);
}
__device__ __forceinline__ float bf16_tof(unsigned short b) {
    return __uint_as_float(((unsigned)b) << 16);
}

// ---------- K1: h = relu(x@W1+b1), hsq, policy, A2 bf16 hi/lo, zero ovcnt ----------
__global__ __launch_bounds__(64) void k_mlp(
    const float* __restrict__ x, const float* __restrict__ W1,
    const float* __restrict__ b1, const float* __restrict__ Wp,
    const float* __restrict__ bp, float* __restrict__ out,
    float* __restrict__ ws_h, float* __restrict__ hsq,
    unsigned* __restrict__ ovcnt, unsigned short* __restrict__ a2)
{
    const int b = blockIdx.x;
    const int j = threadIdx.x;
    const float* xr = x + b * SDIM;
    float a0 = 0.f, a1 = 0.f, a2r = 0.f, a3 = 0.f;
    #pragma unroll 8
    for (int s = 0; s < SDIM; s += 4) {
        a0  = fmaf(xr[s+0], W1[(s+0)*HDIM + j], a0);
        a1  = fmaf(xr[s+1], W1[(s+1)*HDIM + j], a1);
        a2r = fmaf(xr[s+2], W1[(s+2)*HDIM + j], a2r);
        a3  = fmaf(xr[s+3], W1[(s+3)*HDIM + j], a3);
    }
    float h = (a0 + a1) + (a2r + a3) + b1[j];
    h = fmaxf(h, 0.f);
    ws_h[b*HDIM + j] = h;
    out[OUT_H_OFF + b*HDIM + j] = h;

    unsigned short hi = bf16_rne(h);
    float lof = h - bf16_tof(hi);
    unsigned short lo = bf16_rne(lof);
    a2[b*128 + j]      = hi;
    a2[b*128 + 64 + j] = lo;

    float sq = h * h;
    #pragma unroll
    for (int m = 32; m >= 1; m >>= 1) sq += __shfl_xor(sq, m, 64);
    if (j == 0) { hsq[b] = sq; ovcnt[b] = 0u; }

    __shared__ float hl[HDIM];
    hl[j] = h;
    __syncthreads();
    if (j < ADIM) {
        float p = bp[j];
        #pragma unroll 8
        for (int k = 0; k < HDIM; k++) p = fmaf(hl[k], Wp[k*ADIM + j], p);
        out[b*ADIM + j] = p;
    }
}

// ---------- K2: ksq ----------
__global__ __launch_bounds__(256) void k_ksq(
    const float* __restrict__ keys, float* __restrict__ ksq)
{
    const int t = threadIdx.x;
    const int key = blockIdx.x * 16 + (t >> 4);
    const int l = t & 15;
    float4 v = *(const float4*)(keys + (size_t)key * HDIM + l * 4);
    float s = v.x*v.x + v.y*v.y + v.z*v.z + v.w*v.w;
    s += __shfl_xor(s, 1, 64);
    s += __shfl_xor(s, 2, 64);
    s += __shfl_xor(s, 4, 64);
    s += __shfl_xor(s, 8, 64);
    if (l == 0) ksq[key] = s;
}

// ---------- K3: per-row threshold = RANKSEL-th smallest among keys[0..SAMPLE) ----------
// 2 waves/block, one row per wave. blocks = 512.
__global__ __launch_bounds__(128) void k_thresh(
    const float* __restrict__ keys, const float* __restrict__ ws_h,
    const float* __restrict__ hsq, const float* __restrict__ ksq,
    float* __restrict__ thr)
{
    __shared__ float hrow[2][HDIM];
    __shared__ float dbuf[2][SAMPLE];   // 32 KB
    const int t = threadIdx.x;
    const int wv = t >> 6;
    const int l = t & 63;
    const int row = blockIdx.x * 2 + wv;

    hrow[wv][l] = ws_h[(size_t)row * HDIM + l];
    __syncthreads();
    const float hs = hsq[row];

    for (int m = 0; m < SAMPLE / 64; m++) {
        const int k = l + 64 * m;
        const float* kr = keys + (size_t)k * HDIM;
        float acc = 0.f;
        #pragma unroll
        for (int d = 0; d < HDIM; d += 4) {
            float4 kv = *(const float4*)(kr + d);
            acc = fmaf(hrow[wv][d+0], kv.x, acc);
            acc = fmaf(hrow[wv][d+1], kv.y, acc);
            acc = fmaf(hrow[wv][d+2], kv.z, acc);
            acc = fmaf(hrow[wv][d+3], kv.w, acc);
        }
        dbuf[wv][k] = hs + ksq[k] - 2.f * acc;
    }
    __syncthreads();

    float tval = 0.f;
    for (int it = 0; it < RANKSEL; it++) {
        float best = __uint_as_float(0x7F800000);
        int bslot = 0;
        for (int m = 0; m < SAMPLE / 64; m++) {
            float vv = dbuf[wv][l + 64 * m];
            if (vv < best) { best = vv; bslot = l + 64 * m; }
        }
        ull p = ((ull)ford(best) << 32) | (unsigned)bslot;
        #pragma unroll
        for (int m = 1; m < 64; m <<= 1) {
            ull q = __shfl_xor(p, m, 64);
            if (q < p) p = q;
        }
        if (l == 0) dbuf[wv][(int)(unsigned)p] = __uint_as_float(0x7F800000);
        if (it == RANKSEL - 1) tval = funord((unsigned)(p >> 32));
        __syncthreads();
    }
    if (l == 0) thr[row] = tval;
}

// ---------- K4: MFMA split-bf16 distance GEMM, ballot-compacted candidates ----------
// Tile 128 rows x 128 keys, 4 waves 2x2, each wave 64x64.
// Candidates: per-(row, xblock, colhalf) slice of SL entries, plain stores;
// overflow -> per-row global list via leader-aggregated atomic (rare).
__global__ __launch_bounds__(256, 2) void k_dist(
    const float* __restrict__ keys, const unsigned short* __restrict__ a2,
    const float* __restrict__ hsq, const float* __restrict__ ksq,
    const float* __restrict__ thr,
    int* __restrict__ cnt2, unsigned* __restrict__ ovcnt,
    float* __restrict__ ov_d, int* __restrict__ ov_i,
    float* __restrict__ cand_d, int* __restrict__ cand_i,
    int SL, int OVCAP)
{
    __shared__ short8 Bl[16][128];   // 32 KB

    const int t    = threadIdx.x;
    const int w    = t >> 6;
    const int lane = t & 63;
    const int wr0  = (w >> 1) * 64;
    const int wc0  = (w & 1) * 64;
    const int half = w & 1;
    const int l15  = lane & 15;
    const int l4   = lane >> 4;
    const int row0 = blockIdx.y * 128;
    const int bx   = blockIdx.x;

    // A fragments: a[mf][at], at = {hi0,hi1,lo0,lo1} at elem offsets {0,32,64,96}
    short8 a[4][4];
    #pragma unroll
    for (int mf = 0; mf < 4; mf++) {
        int row = row0 + wr0 + mf * 16 + l15;
        #pragma unroll
        for (int at = 0; at < 4; at++)
            a[mf][at] = *(const short8*)(a2 + (size_t)row * 128 + at * 32 + l4 * 8);
    }

    // filter limits: s < (thr - hsq)/2 where s = ksq/2 - dot
    float lim[4][4];
    int   cntr[4][4];
    #pragma unroll
    for (int mf = 0; mf < 4; mf++)
        #pragma unroll
        for (int rg = 0; rg < 4; rg++) {
            int r = row0 + wr0 + mf * 16 + l4 * 4 + rg;
            lim[mf][rg] = (thr[r] - hsq[r]) * 0.5f;
            cntr[mf][rg] = 0;
        }

    const int skey  = t >> 1;      // 0..127
    const int spart = t & 1;       // dims part*32..+31

    // prologue: load tile bx (always fully in range: keys < 8192)
    float4 f[8];
    {
        const float4* kp = (const float4*)(keys + (size_t)(bx * 128 + skey) * HDIM + spart * 32);
        #pragma unroll
        for (int i = 0; i < 8; i++) f[i] = kp[i];
    }

    for (int j = 0; j < JMAX; j++) {
        const int cur = bx + j * XB;
        if (cur >= NTILES) break;

        // convert staged floats -> hi/lo bf16 (truncation split; lo captures residue)
        short8 Hh[4], Ll[4];
        #pragma unroll
        for (int i = 0; i < 4; i++) {
            float fv[8] = { f[2*i].x, f[2*i].y, f[2*i].z, f[2*i].w,
                            f[2*i+1].x, f[2*i+1].y, f[2*i+1].z, f[2*i+1].w };
            #pragma unroll
            for (int q = 0; q < 8; q++) {
                unsigned u = __float_as_uint(fv[q]);
                unsigned short hb = (unsigned short)(u >> 16);
                float lf = fv[q] - __uint_as_float(u & 0xFFFF0000u);
                unsigned short lb = (unsigned short)(__float_as_uint(lf) >> 16);
                Hh[i][q] = (short)hb;
                Ll[i][q] = (short)lb;
            }
        }

        __syncthreads();             // (A) prev tile's LDS reads done; no vmem in flight here
        #pragma unroll
        for (int i = 0; i < 4; i++) {
            Bl[spart*4 + i][skey]     = Hh[i];
            Bl[8 + spart*4 + i][skey] = Ll[i];
        }
        __syncthreads();             // (B) B tile ready

        // issue next-tile loads NOW: they cross no barrier until consumed
        // at the top of the next iteration (hidden under MFMA + epilogue).
        {
            int nxt = cur + XB;
            if (nxt < NTILES) {
                int kg = nxt * 128 + skey;
                if (kg < NKEYS) {
                    const float4* kp = (const float4*)(keys + (size_t)kg * HDIM + spart * 32);
                    #pragma unroll
                    for (int i = 0; i < 8; i++) f[i] = kp[i];
                } else {
                    #pragma unroll
                    for (int i = 0; i < 8; i++) f[i] = make_float4(0.f,0.f,0.f,0.f);
                }
            }
        }

        float kh[4];
        #pragma unroll
        for (int nf = 0; nf < 4; nf++) {
            int col = cur * 128 + wc0 + nf * 16 + l15;
            kh[nf] = (col < NKEYS) ? 0.5f * ksq[col] : 3.0e37f;
        }

        f32x4 acc[4][4];
        #pragma unroll
        for (int mf = 0; mf < 4; mf++)
            #pragma unroll
            for (int nf = 0; nf < 4; nf++)
                acc[mf][nf] = (f32x4){0.f,0.f,0.f,0.f};

        #pragma unroll
        for (int bt = 0; bt < 4; bt++) {
            short8 bf[4];
            #pragma unroll
            for (int nf = 0; nf < 4; nf++)
                bf[nf] = Bl[bt*4 + l4][wc0 + nf*16 + l15];

            const int at0 = (bt < 2) ? bt : (bt - 2);
            #pragma unroll
            for (int mf = 0; mf < 4; mf++)
                #pragma unroll
                for (int nf = 0; nf < 4; nf++)
                    acc[mf][nf] = __builtin_amdgcn_mfma_f32_16x16x32_bf16(
                        a[mf][at0], bf[nf], acc[mf][nf], 0, 0, 0);
            if (bt < 2) {
                const int at1 = bt + 2;
                #pragma unroll
                for (int mf = 0; mf < 4; mf++)
                    #pragma unroll
                    for (int nf = 0; nf < 4; nf++)
                        acc[mf][nf] = __builtin_amdgcn_mfma_f32_16x16x32_bf16(
                            a[mf][at1], bf[nf], acc[mf][nf], 0, 0, 0);
            }
        }

        // epilogue: ballot-compacted candidate append (no atomics on fast path)
        #pragma unroll
        for (int mf = 0; mf < 4; mf++)
            #pragma unroll
            for (int nf = 0; nf < 4; nf++)
                #pragma unroll
                for (int rg = 0; rg < 4; rg++) {
                    float s = kh[nf] - acc[mf][nf][rg];
                    bool hit = s < lim[mf][rg];
                    ull bal = __ballot(hit);
                    if (bal == 0) continue;          // wave-uniform skip
                    unsigned grp = (unsigned)((bal >> (l4*16)) & 0xFFFFull);
                    int pre = __popc(grp & ((1u << l15) - 1u));
                    int pos = cntr[mf][rg] + pre;
                    cntr[mf][rg] += __popc(grp);
                    int row = row0 + wr0 + mf*16 + l4*4 + rg;
                    int col = cur*128 + wc0 + nf*16 + l15;
                    if (hit && pos < SL) {
                        size_t sb = ((size_t)row * 128 + bx*2 + half) * (size_t)SL + pos;
                        cand_d[sb] = s;
                        cand_i[sb] = col;
                    }
                    ull balov = __ballot(hit && pos >= SL);
                    if (balov != 0) {
                        unsigned g2 = (unsigned)((balov >> (l4*16)) & 0xFFFFull);
                        unsigned base = 0;
                        int ldr = __ffs(g2) - 1;     // valid only if g2!=0
                        if (g2 != 0 && l15 == ldr)
                            base = atomicAdd(&ovcnt[row], (unsigned)__popc(g2));
                        if (g2 != 0) {
                            base = __shfl(base, l4*16 + ldr, 64);
                            if (hit && pos >= SL) {
                                int p2 = (int)base + __popc(g2 & ((1u << l15) - 1u));
                                if (p2 < OVCAP) {
                                    ov_d[(size_t)row * OVCAP + p2] = s;
                                    ov_i[(size_t)row * OVCAP + p2] = col;
                                }
                            }
                        }
                    }
                }
    }

    // final slice counts (plain stores)
    if (l15 == 0) {
        #pragma unroll
        for (int mf = 0; mf < 4; mf++)
            #pragma unroll
            for (int rg = 0; rg < 4; rg++) {
                int row = row0 + wr0 + mf*16 + l4*4 + rg;
                cnt2[(size_t)row * 128 + bx*2 + half] = cntr[mf][rg];
            }
    }
}

// ---------- K5: gather slices+overflow -> approx top-NS -> exact recompute -> top-50 ----------
__global__ __launch_bounds__(256) void k_merge(
    const float* __restrict__ cand_d, const int* __restrict__ cand_i,
    const int* __restrict__ cnt2, const unsigned* __restrict__ ovcnt,
    const float* __restrict__ ov_d, const int* __restrict__ ov_i,
    const float* __restrict__ vals, const float* __restrict__ keys,
    const float* __restrict__ ws_h, const float* __restrict__ hsq,
    const float* __restrict__ ksq, float* __restrict__ out_val,
    int SL, int OVCAP)
{
    __shared__ ull wred2[4];
    __shared__ ull win[NS];
    __shared__ float hrow_s[HDIM];
    __shared__ float dex[NS];

    const int r = blockIdx.x;
    const int t = threadIdx.x;

    if (t < HDIM) hrow_s[t] = ws_h[(size_t)r * HDIM + t];

    ull v[24];
    #pragma unroll
    for (int i = 0; i < 24; i++) v[i] = ~0ull;

    // slice candidates: slice s = t>>1, items (t&1)+2k
    {
        int s = t >> 1, sub = t & 1;
        int cs = cnt2[(size_t)r * 128 + s];
        if (cs > SL) cs = SL;
        size_t sb = ((size_t)r * 128 + s) * (size_t)SL;
        #pragma unroll
        for (int k2 = 0; k2 < 8; k2++) {
            int i = sub + 2*k2;
            if (i < cs)
                v[k2] = ((ull)ford(cand_d[sb+i]) << 32) | (unsigned)cand_i[sb+i];
        }
    }
    // overflow list: items t + 256k
    {
        int oc = (int)ovcnt[r];
        if (oc > OVCAP) oc = OVCAP;
        #pragma unroll
        for (int k2 = 0; k2 < 16; k2++) {
            int i = t + 256*k2;
            if (i < oc)
                v[8+k2] = ((ull)ford(ov_d[(size_t)r * OVCAP + i]) << 32)
                        | (unsigned)ov_i[(size_t)r * OVCAP + i];
        }
    }
    __syncthreads();

    // extract NS smallest (approx score, idx tiebreak)
    for (int e = 0; e < NS; e++) {
        ull m = v[0];
        #pragma unroll
        for (int i = 1; i < 24; i++) m = (v[i] < m) ? v[i] : m;
        ull wm = m;
        #pragma unroll
        for (int mm = 1; mm < 64; mm <<= 1) {
            ull o = __shfl_xor(wm, mm, 64);
            wm = (o < wm) ? o : wm;
        }
        if ((t & 63) == 0) wred2[t >> 6] = wm;
        __syncthreads();
        ull g = wred2[0];
        if (wred2[1] < g) g = wred2[1];
        if (wred2[2] < g) g = wred2[2];
        if (wred2[3] < g) g = wred2[3];
        if (m == g && g != ~0ull) {
            #pragma unroll
            for (int i = 0; i < 24; i++) if (v[i] == g) v[i] = ~0ull;
        }
        if (t == 0) win[e] = g;
        __syncthreads();
    }

    // exact fp32 distance for NS winners
    if (t < NS) {
        ull g = win[t];
        float dv = 3.0e38f;
        if (g != ~0ull) {
            int idx = (int)(unsigned)g;
            const float4* kp = (const float4*)(keys + (size_t)idx * HDIM);
            float acc = 0.f;
            #pragma unroll
            for (int q = 0; q < 16; q++) {
                float4 kv = kp[q];
                acc = fmaf(hrow_s[4*q+0], kv.x, acc);
                acc = fmaf(hrow_s[4*q+1], kv.y, acc);
                acc = fmaf(hrow_s[4*q+2], kv.z, acc);
                acc = fmaf(hrow_s[4*q+3], kv.w, acc);
            }
            dv = fmaxf(hsq[r] + ksq[idx] - 2.f * acc, 0.f);
        }
        dex[t] = dv;
    }
    __syncthreads();

    // exact top-50 by rank, weighted sum (wave 0)
    if (t < 64) {
        float dv = (t < NS) ? dex[t] : 3.0e38f;
        unsigned idx = (t < NS) ? (unsigned)win[t] : 0xFFFFFFFFu;
        ull me = ((ull)ford(dv) << 32) | idx;
        int rank = 0;
        for (int j2 = 0; j2 < NS; j2++) {
            ull o = __shfl(me, j2, 64);
            rank += (o < me) ? 1 : 0;
        }
        float wsum = 0.f, wv = 0.f;
        if (rank < K_NB && dv < 1.0e38f) {
            float wgt = 1.f / (dv + DELTA);
            wsum = wgt;
            wv = wgt * vals[idx];
        }
        #pragma unroll
        for (int m = 1; m < 64; m <<= 1) {
            wsum += __shfl_xor(wsum, m, 64);
            wv   += __shfl_xor(wv,   m, 64);
        }
        if (t == 0) out_val[r] = wv / wsum;
    }
}

// ---------- launch ----------
extern "C" void kernel_launch(void* const* d_in, const int* in_sizes, int n_in,
                              void* d_out, int out_size, void* d_ws, size_t ws_size,
                              hipStream_t stream)
{
    const float* x    = (const float*)d_in[0];
    const float* W1   = (const float*)d_in[1];
    const float* b1   = (const float*)d_in[2];
    const float* Wp   = (const float*)d_in[3];
    const float* bp   = (const float*)d_in[4];
    const float* keys = (const float*)d_in[5];
    const float* vals = (const float*)d_in[6];
    float* out = (float*)d_out;
    float* ws  = (float*)d_ws;

    // ws layout (float units)
    float*          ws_h  = ws;                               // 65536
    float*          hsq   = ws + 65536;                       // 1024
    float*          ksq   = ws + 66560;                       // 200704 (padded)
    float*          thr   = ws + 267264;                      // 1024
    unsigned short* a2    = (unsigned short*)(ws + 268288);   // 65536 floats
    int*            cnt2  = (int*)(ws + 333824);              // 131072
    unsigned*       ovcnt = (unsigned*)(ws + 464896);         // 1024
    const size_t basef = 465920;

    int SL, OVCAP;
    const size_t fast_need = basef + 2ull*1024*768 + 2ull*1024*128*16;  // 6,233,088 floats
    if (ws_size >= fast_need * 4ull) {
        SL = 16; OVCAP = 768;
    } else {
        SL = 0;
        long avail = (long)(ws_size / 4) - (long)basef;
        long oc = avail / 2048;
        OVCAP = (int)oc;
        if (OVCAP > 4096) OVCAP = 4096;
        if (OVCAP < 256)  OVCAP = 256;
    }
    float* ov_d   = ws + basef;
    int*   ov_i   = (int*)(ov_d + (size_t)1024 * OVCAP);
    float* cand_d = (float*)(ov_i + (size_t)1024 * OVCAP);
    int*   cand_i = (int*)(cand_d + (size_t)1024 * 128 * SL);

    k_mlp<<<BROWS, 64, 0, stream>>>(x, W1, b1, Wp, bp, out, ws_h, hsq, ovcnt, a2);
    k_ksq<<<NKEYS / 16, 256, 0, stream>>>(keys, ksq);
    k_thresh<<<BROWS / 2, 128, 0, stream>>>(keys, ws_h, hsq, ksq, thr);
    dim3 gdist(XB, 8);
    k_dist<<<gdist, 256, 0, stream>>>(keys, a2, hsq, ksq, thr, cnt2, ovcnt,
                                      ov_d, ov_i, cand_d, cand_i, SL, OVCAP);
    k_merge<<<BROWS, 256, 0, stream>>>(cand_d, cand_i, cnt2, ovcnt, ov_d, ov_i,
                                       vals, keys, ws_h, hsq, ksq,
                                       out + OUT_VAL_OFF, SL, OVCAP);
}

// Round 4
// 560.048 us; speedup vs baseline: 1.7519x; 1.2422x over previous
//
#include <hip/hip_runtime.h>
#include <hip/hip_bf16.h>
#include <stdint.h>

#define K_NB    50
#define DELTA   1e-3f
#define NKEYS   200000
#define BROWS   1024
#define HDIM    64
#define SDIM    256
#define ADIM    18
#define NS      80          // pre-selection width (exact top-50 subset, covers q16 reorder)
#define XB      64          // x-blocks in k_dist
#define JMAX    25          // ceil(NTILES/XB)
#define NTILES  1563        // ceil(200000/128)
#define OVCAP   256         // per-row overflow list entries

// out layout (floats): policy [0,18432) | value [18432,19456) | h [19456,84992)
#define OUT_VAL_OFF 18432
#define OUT_H_OFF   19456

typedef __attribute__((ext_vector_type(8))) short short8;
typedef __attribute__((ext_vector_type(4))) float f32x4;
typedef unsigned long long ull;

__device__ __forceinline__ unsigned ford(float f) {
    unsigned u = __float_as_uint(f);
    return (u & 0x80000000u) ? ~u : (u | 0x80000000u);
}
__device__ __forceinline__ float funord(unsigned u) {
    u = (u & 0x80000000u) ? (u & 0x7FFFFFFFu) : ~u;
    return __uint_as_float(u);
}
__device__ __forceinline__ unsigned short bf16_rne(float f) {
    unsigned u = __float_as_uint(f);
    unsigned r = u + 0x7FFFu + ((u >> 16) & 1u);
    return (unsigned short)(r >> 16);
}
__device__ __forceinline__ float bf16_tof(unsigned short b) {
    return __uint_as_float(((unsigned)b) << 16);
}

// ---------- K1: h = relu(x@W1+b1), hsq, policy, A2 bf16 hi/lo, zero ovcnt ----------
__global__ __launch_bounds__(64) void k_mlp(
    const float* __restrict__ x, const float* __restrict__ W1,
    const float* __restrict__ b1, const float* __restrict__ Wp,
    const float* __restrict__ bp, float* __restrict__ out,
    float* __restrict__ ws_h, float* __restrict__ hsq,
    unsigned* __restrict__ ovcnt, unsigned short* __restrict__ a2)
{
    const int b = blockIdx.x;
    const int j = threadIdx.x;
    const float* xr = x + b * SDIM;
    float a0 = 0.f, a1 = 0.f, a2r = 0.f, a3 = 0.f;
    #pragma unroll 8
    for (int s = 0; s < SDIM; s += 4) {
        a0  = fmaf(xr[s+0], W1[(s+0)*HDIM + j], a0);
        a1  = fmaf(xr[s+1], W1[(s+1)*HDIM + j], a1);
        a2r = fmaf(xr[s+2], W1[(s+2)*HDIM + j], a2r);
        a3  = fmaf(xr[s+3], W1[(s+3)*HDIM + j], a3);
    }
    float h = (a0 + a1) + (a2r + a3) + b1[j];
    h = fmaxf(h, 0.f);
    ws_h[b*HDIM + j] = h;
    out[OUT_H_OFF + b*HDIM + j] = h;

    unsigned u = __float_as_uint(h);
    unsigned short hi = (unsigned short)(u >> 16);        // trunc split
    float lf = h - __uint_as_float(u & 0xFFFF0000u);
    unsigned short lo = bf16_rne(lf);
    a2[b*128 + j]      = hi;
    a2[b*128 + 64 + j] = lo;

    float sq = h * h;
    #pragma unroll
    for (int m = 32; m >= 1; m >>= 1) sq += __shfl_xor(sq, m, 64);
    if (j == 0) { hsq[b] = sq; ovcnt[b] = 0u; }

    __shared__ float hl[HDIM];
    hl[j] = h;
    __syncthreads();
    if (j < ADIM) {
        float p = bp[j];
        #pragma unroll 8
        for (int k = 0; k < HDIM; k++) p = fmaf(hl[k], Wp[k*ADIM + j], p);
        out[b*ADIM + j] = p;
    }
}

// ---------- K2: ksq ----------
__global__ __launch_bounds__(256) void k_ksq(
    const float* __restrict__ keys, float* __restrict__ ksq)
{
    const int t = threadIdx.x;
    const int key = blockIdx.x * 16 + (t >> 4);
    const int l = t & 15;
    float4 v = *(const float4*)(keys + (size_t)key * HDIM + l * 4);
    float s = v.x*v.x + v.y*v.y + v.z*v.z + v.w*v.w;
    s += __shfl_xor(s, 1, 64);
    s += __shfl_xor(s, 2, 64);
    s += __shfl_xor(s, 4, 64);
    s += __shfl_xor(s, 8, 64);
    if (l == 0) ksq[key] = s;
}

// ---------- K3a: sample distance GEMM -> u16 quantized d, one tile per block ----------
__global__ __launch_bounds__(256, 2) void k_sdist(
    const float* __restrict__ keys, const unsigned short* __restrict__ a2,
    const float* __restrict__ hsq, const float* __restrict__ ksq,
    unsigned short* __restrict__ d_sample, int sample)
{
    __shared__ short8 Bl[16][132];   // padded stride: 4-way -> 2-way (free)

    const int t    = threadIdx.x;
    const int w    = t >> 6;
    const int lane = t & 63;
    const int wr0  = (w >> 1) * 64;
    const int wc0  = (w & 1) * 64;
    const int l15  = lane & 15;
    const int l4   = lane >> 4;
    const int row0 = blockIdx.y * 128;
    const int n0   = blockIdx.x * 128;

    short8 a[4][4];
    #pragma unroll
    for (int mf = 0; mf < 4; mf++) {
        int row = row0 + wr0 + mf * 16 + l15;
        #pragma unroll
        for (int at = 0; at < 4; at++)
            a[mf][at] = *(const short8*)(a2 + (size_t)row * 128 + at * 32 + l4 * 8);
    }
    float hs_r[4][4];
    #pragma unroll
    for (int mf = 0; mf < 4; mf++)
        #pragma unroll
        for (int rg = 0; rg < 4; rg++)
            hs_r[mf][rg] = hsq[row0 + wr0 + mf*16 + l4*4 + rg];

    const int skey  = t >> 1;
    const int spart = t & 1;
    float4 f[8];
    {
        const float4* kp = (const float4*)(keys + (size_t)(n0 + skey) * HDIM + spart * 32);
        #pragma unroll
        for (int i = 0; i < 8; i++) f[i] = kp[i];
    }
    short8 Hh[4], Ll[4];
    #pragma unroll
    for (int i = 0; i < 4; i++) {
        float fv[8] = { f[2*i].x, f[2*i].y, f[2*i].z, f[2*i].w,
                        f[2*i+1].x, f[2*i+1].y, f[2*i+1].z, f[2*i+1].w };
        #pragma unroll
        for (int q = 0; q < 8; q++) {
            unsigned u = __float_as_uint(fv[q]);
            Hh[i][q] = (short)(u >> 16);
            float lf = fv[q] - __uint_as_float(u & 0xFFFF0000u);
            Ll[i][q] = (short)(__float_as_uint(lf) >> 16);
        }
    }
    #pragma unroll
    for (int i = 0; i < 4; i++) {
        Bl[spart*4 + i][skey]     = Hh[i];
        Bl[8 + spart*4 + i][skey] = Ll[i];
    }
    __syncthreads();

    float kh[4];
    #pragma unroll
    for (int nf = 0; nf < 4; nf++)
        kh[nf] = 0.5f * ksq[n0 + wc0 + nf * 16 + l15];

    f32x4 acc[4][4];
    #pragma unroll
    for (int mf = 0; mf < 4; mf++)
        #pragma unroll
        for (int nf = 0; nf < 4; nf++)
            acc[mf][nf] = (f32x4){0.f,0.f,0.f,0.f};

    #pragma unroll
    for (int bt = 0; bt < 4; bt++) {
        short8 bf[4];
        #pragma unroll
        for (int nf = 0; nf < 4; nf++)
            bf[nf] = Bl[bt*4 + l4][wc0 + nf*16 + l15];
        const int at0 = (bt < 2) ? bt : (bt - 2);
        #pragma unroll
        for (int mf = 0; mf < 4; mf++)
            #pragma unroll
            for (int nf = 0; nf < 4; nf++)
                acc[mf][nf] = __builtin_amdgcn_mfma_f32_16x16x32_bf16(
                    a[mf][at0], bf[nf], acc[mf][nf], 0, 0, 0);
        if (bt < 2) {
            const int at1 = bt + 2;
            #pragma unroll
            for (int mf = 0; mf < 4; mf++)
                #pragma unroll
                for (int nf = 0; nf < 4; nf++)
                    acc[mf][nf] = __builtin_amdgcn_mfma_f32_16x16x32_bf16(
                        a[mf][at1], bf[nf], acc[mf][nf], 0, 0, 0);
        }
    }

    #pragma unroll
    for (int mf = 0; mf < 4; mf++)
        #pragma unroll
        for (int nf = 0; nf < 4; nf++)
            #pragma unroll
            for (int rg = 0; rg < 4; rg++) {
                int row = row0 + wr0 + mf*16 + l4*4 + rg;
                int col = n0 + wc0 + nf*16 + l15;
                float s = kh[nf] - acc[mf][nf][rg];
                float d = fmaf(2.f, s, hs_r[mf][rg]);
                d_sample[(size_t)row * sample + col] = (unsigned short)(ford(d) >> 16);
            }
}

// ---------- K3b: rank-select threshold from quantized sample distances ----------
// 4 rows per block (one per wave).
__global__ __launch_bounds__(256) void k_sel(
    const unsigned short* __restrict__ d_sample, float* __restrict__ thr,
    int sample, int rank)
{
    __shared__ unsigned sbuf[4][2048];     // up to 4096 u16 per row
    const int t = threadIdx.x;
    const int wv = t >> 6;
    const int l = t & 63;
    const int row = blockIdx.x * 4 + wv;

    const int nvec = sample >> 3;          // uint4 count per row
    const uint4* gp = (const uint4*)(d_sample + (size_t)row * sample);
    for (int q = 0; q < nvec / 64; q++) {
        uint4 vv = gp[l + 64*q];
        int bidx = (l + 64*q) * 4;
        sbuf[wv][bidx+0] = vv.x; sbuf[wv][bidx+1] = vv.y;
        sbuf[wv][bidx+2] = vv.z; sbuf[wv][bidx+3] = vv.w;
    }
    __syncthreads();

    const int nscan = sample >> 7;         // u32 words per lane
    float tval = 0.f;
    for (int it = 0; it < rank; it++) {
        unsigned best = 0xFFFFFFFFu;
        for (int m = 0; m < nscan; m++) {
            unsigned wd = sbuf[wv][l + 64*m];
            unsigned slot2 = (unsigned)((l + 64*m) * 2);
            unsigned klo = ((wd & 0xFFFFu) << 12) | slot2;
            unsigned khi = ((wd >> 16) << 12) | (slot2 + 1);
            unsigned kk = (klo < khi) ? klo : khi;
            best = (kk < best) ? kk : best;
        }
        #pragma unroll
        for (int m = 1; m < 64; m <<= 1) {
            unsigned o = __shfl_xor(best, m, 64);
            best = (o < best) ? o : best;
        }
        if (l == 0) {
            unsigned slot = best & 0xFFFu;
            unsigned wd = sbuf[wv][slot >> 1];
            wd |= (slot & 1) ? 0xFFFF0000u : 0x0000FFFFu;
            sbuf[wv][slot >> 1] = wd;
        }
        if (it == rank - 1) tval = funord((best >> 12) << 16);
        __syncthreads();
    }
    if (l == 0) thr[row] = tval;
}

// ---------- K4: MFMA split-bf16 distance GEMM, LDS-compacted candidates ----------
__global__ __launch_bounds__(256, 2) void k_dist(
    const float* __restrict__ keys, const unsigned short* __restrict__ a2,
    const float* __restrict__ hsq, const float* __restrict__ ksq,
    const float* __restrict__ thr, int* __restrict__ cnt2,
    unsigned* __restrict__ ovcnt, ull* __restrict__ ov,
    unsigned* __restrict__ cand, int cap)
{
    __shared__ short8 Bl[16][132];            // 33792 B, padded stride
    __shared__ unsigned cand_lds[128 * 32];   // 16384 B
    __shared__ unsigned lds_cnt[128];

    const int t    = threadIdx.x;
    const int w    = t >> 6;
    const int lane = t & 63;
    const int wr0  = (w >> 1) * 64;
    const int wc0  = (w & 1) * 64;
    const int l15  = lane & 15;
    const int l4   = lane >> 4;
    const int row0 = blockIdx.y * 128;
    const int bx   = blockIdx.x;

    if (t < 128) lds_cnt[t] = 0u;

    short8 a[4][4];
    #pragma unroll
    for (int mf = 0; mf < 4; mf++) {
        int row = row0 + wr0 + mf * 16 + l15;
        #pragma unroll
        for (int at = 0; at < 4; at++)
            a[mf][at] = *(const short8*)(a2 + (size_t)row * 128 + at * 32 + l4 * 8);
    }
    float lim[4][4];
    #pragma unroll
    for (int mf = 0; mf < 4; mf++)
        #pragma unroll
        for (int rg = 0; rg < 4; rg++) {
            int r = row0 + wr0 + mf * 16 + l4 * 4 + rg;
            lim[mf][rg] = (thr[r] - hsq[r]) * 0.5f;
        }

    const int skey  = t >> 1;
    const int spart = t & 1;
    float4 f[8];
    {
        const float4* kp = (const float4*)(keys + (size_t)(bx * 128 + skey) * HDIM + spart * 32);
        #pragma unroll
        for (int i = 0; i < 8; i++) f[i] = kp[i];
    }

    for (int j = 0; j < JMAX; j++) {
        const int cur = bx + j * XB;
        if (cur >= NTILES) break;

        short8 Hh[4], Ll[4];
        #pragma unroll
        for (int i = 0; i < 4; i++) {
            float fv[8] = { f[2*i].x, f[2*i].y, f[2*i].z, f[2*i].w,
                            f[2*i+1].x, f[2*i+1].y, f[2*i+1].z, f[2*i+1].w };
            #pragma unroll
            for (int q = 0; q < 8; q++) {
                unsigned u = __float_as_uint(fv[q]);
                Hh[i][q] = (short)(u >> 16);
                float lf = fv[q] - __uint_as_float(u & 0xFFFF0000u);
                Ll[i][q] = (short)(__float_as_uint(lf) >> 16);
            }
        }

        __syncthreads();             // (A) prev tile's Bl reads done
        #pragma unroll
        for (int i = 0; i < 4; i++) {
            Bl[spart*4 + i][skey]     = Hh[i];
            Bl[8 + spart*4 + i][skey] = Ll[i];
        }
        __syncthreads();             // (B) B tile ready

        // prefetch next tile: crosses no barrier until consumed next iter
        {
            int nxt = cur + XB;
            if (nxt < NTILES) {
                int kg = nxt * 128 + skey;
                if (kg < NKEYS) {
                    const float4* kp = (const float4*)(keys + (size_t)kg * HDIM + spart * 32);
                    #pragma unroll
                    for (int i = 0; i < 8; i++) f[i] = kp[i];
                } else {
                    #pragma unroll
                    for (int i = 0; i < 8; i++) f[i] = make_float4(0.f,0.f,0.f,0.f);
                }
            }
        }

        float kh[4];
        #pragma unroll
        for (int nf = 0; nf < 4; nf++) {
            int col = cur * 128 + wc0 + nf * 16 + l15;
            kh[nf] = (col < NKEYS) ? 0.5f * ksq[col] : 3.0e37f;
        }

        f32x4 acc[4][4];
        #pragma unroll
        for (int mf = 0; mf < 4; mf++)
            #pragma unroll
            for (int nf = 0; nf < 4; nf++)
                acc[mf][nf] = (f32x4){0.f,0.f,0.f,0.f};

        #pragma unroll
        for (int bt = 0; bt < 4; bt++) {
            short8 bf[4];
            #pragma unroll
            for (int nf = 0; nf < 4; nf++)
                bf[nf] = Bl[bt*4 + l4][wc0 + nf*16 + l15];
            const int at0 = (bt < 2) ? bt : (bt - 2);
            #pragma unroll
            for (int mf = 0; mf < 4; mf++)
                #pragma unroll
                for (int nf = 0; nf < 4; nf++)
                    acc[mf][nf] = __builtin_amdgcn_mfma_f32_16x16x32_bf16(
                        a[mf][at0], bf[nf], acc[mf][nf], 0, 0, 0);
            if (bt < 2) {
                const int at1 = bt + 2;
                #pragma unroll
                for (int mf = 0; mf < 4; mf++)
                    #pragma unroll
                    for (int nf = 0; nf < 4; nf++)
                        acc[mf][nf] = __builtin_amdgcn_mfma_f32_16x16x32_bf16(
                            a[mf][at1], bf[nf], acc[mf][nf], 0, 0, 0);
            }
        }

        // epilogue: ballot-compacted append into LDS slices
        #pragma unroll
        for (int mf = 0; mf < 4; mf++)
            #pragma unroll
            for (int nf = 0; nf < 4; nf++)
                #pragma unroll
                for (int rg = 0; rg < 4; rg++) {
                    float s = kh[nf] - acc[mf][nf][rg];
                    bool hit = s < lim[mf][rg];
                    ull bal = __ballot(hit);
                    if (bal == 0) continue;
                    unsigned grp = (unsigned)((bal >> (l4*16)) & 0xFFFFull);
                    int lrow = wr0 + mf*16 + l4*4 + rg;
                    unsigned base = 0;
                    if (grp != 0) {
                        int ldr = __ffs(grp) - 1;
                        if (l15 == ldr)
                            base = atomicAdd(&lds_cnt[lrow], (unsigned)__popc(grp));
                        base = __shfl(base, (lane & 48) + ldr, 64);
                    }
                    if (hit) {
                        int pos = (int)base + __popc(grp & ((1u << l15) - 1u));
                        if (pos < cap) {
                            unsigned packed = (ford(s) & 0xFFFF0000u)
                                            | ((unsigned)j << 7) | (unsigned)(wc0 + nf*16 + l15);
                            cand_lds[lrow * 32 + pos] = packed;
                        } else {
                            int grow = row0 + lrow;
                            unsigned p2 = atomicAdd(&ovcnt[grow], 1u);
                            if (p2 < OVCAP)
                                ov[(size_t)grow * OVCAP + p2] =
                                    ((ull)ford(s) << 32) | (unsigned)(cur*128 + wc0 + nf*16 + l15);
                        }
                    }
                }
    }

    __syncthreads();
    // flush: contiguous, fully-dirty lines
    {
        const int lr   = t >> 1;
        const int half = t & 1;
        unsigned c = lds_cnt[lr];
        if (c > (unsigned)cap) c = (unsigned)cap;
        if (half == 0) cnt2[(size_t)(row0 + lr) * XB + bx] = (int)c;
        const int hc = cap >> 1;                      // entries per half (8 or 16)
        unsigned* dst = cand + ((size_t)(row0 + lr) * XB + bx) * cap + half * hc;
        const unsigned* src = &cand_lds[lr * 32 + half * hc];
        for (int i = 0; i < hc / 4; i++)
            ((uint4*)dst)[i] = *(const uint4*)&src[i * 4];
    }
}

// ---------- K5: gather -> approx top-NS -> exact recompute -> exact top-50 ----------
__global__ __launch_bounds__(256) void k_merge(
    const unsigned* __restrict__ cand, const int* __restrict__ cnt2,
    const unsigned* __restrict__ ovcnt, const ull* __restrict__ ov,
    const float* __restrict__ vals, const float* __restrict__ keys,
    const float* __restrict__ ws_h, const float* __restrict__ hsq,
    const float* __restrict__ ksq, float* __restrict__ out_val, int cap)
{
    __shared__ ull wred2[4];
    __shared__ ull win[NS];
    __shared__ float hrow_s[HDIM];
    __shared__ float dexs[NS];
    __shared__ unsigned idxs[NS];
    __shared__ float rs[4], rvs[4];

    const int r = blockIdx.x;
    const int t = threadIdx.x;

    if (t < HDIM) hrow_s[t] = ws_h[(size_t)r * HDIM + t];

    ull v[9];
    #pragma unroll
    for (int i = 0; i < 9; i++) v[i] = ~0ull;

    // slices: slice s = t>>2 (== bx), sub = t&3
    {
        int s = t >> 2, sub = t & 3;
        int cs = cnt2[(size_t)r * XB + s];
        if (cs > cap) cs = cap;
        const unsigned* sp = cand + ((size_t)r * XB + s) * cap;
        for (int k2 = 0; k2 < cap/4; k2++) {
            int i = sub + 4*k2;
            if (i < cs) {
                unsigned p = sp[i];
                unsigned col = (unsigned)((s + (int)((p >> 7) & 31u) * XB) * 128) + (p & 127u);
                v[k2] = ((ull)(p & 0xFFFF0000u) << 16) | col;
            }
        }
    }
    // overflow
    {
        int oc = (int)ovcnt[r];
        if (oc > OVCAP) oc = OVCAP;
        if (t < oc) {
            ull e = ov[(size_t)r * OVCAP + t];
            unsigned fs = (unsigned)(e >> 32);
            unsigned col = (unsigned)e;
            v[8] = ((ull)(fs & 0xFFFF0000u) << 16) | col;
        }
    }
    __syncthreads();

    for (int e = 0; e < NS; e++) {
        ull m = v[0];
        #pragma unroll
        for (int i = 1; i < 9; i++) m = (v[i] < m) ? v[i] : m;
        ull wm = m;
        #pragma unroll
        for (int mm = 1; mm < 64; mm <<= 1) {
            ull o = __shfl_xor(wm, mm, 64);
            wm = (o < wm) ? o : wm;
        }
        if ((t & 63) == 0) wred2[t >> 6] = wm;
        __syncthreads();
        ull g = wred2[0];
        if (wred2[1] < g) g = wred2[1];
        if (wred2[2] < g) g = wred2[2];
        if (wred2[3] < g) g = wred2[3];
        if (m == g && g != ~0ull) {
            #pragma unroll
            for (int i = 0; i < 9; i++) if (v[i] == g) v[i] = ~0ull;
        }
        if (t == 0) win[e] = g;
        __syncthreads();
    }

    // exact fp32 recompute for NS winners
    if (t < NS) {
        ull g = win[t];
        float dv = 3.0e38f;
        unsigned idx = 0xFFFFFFFFu;
        if (g != ~0ull) {
            idx = (unsigned)g;
            const float4* kp = (const float4*)(keys + (size_t)idx * HDIM);
            float acc = 0.f;
            #pragma unroll
            for (int q = 0; q < 16; q++) {
                float4 kv = kp[q];
                acc = fmaf(hrow_s[4*q+0], kv.x, acc);
                acc = fmaf(hrow_s[4*q+1], kv.y, acc);
                acc = fmaf(hrow_s[4*q+2], kv.z, acc);
                acc = fmaf(hrow_s[4*q+3], kv.w, acc);
            }
            dv = fmaxf(hsq[r] + ksq[idx] - 2.f * acc, 0.f);
        }
        dexs[t] = dv;
        idxs[t] = idx;
    }
    __syncthreads();

    float cw = 0.f, cwv = 0.f;
    if (t < NS && idxs[t] != 0xFFFFFFFFu) {
        float dv = dexs[t];
        unsigned idx = idxs[t];
        unsigned fd = ford(dv);
        int rk = 0;
        for (int q = 0; q < NS; q++) {
            unsigned fq = ford(dexs[q]);
            rk += ((fq < fd) || (fq == fd && idxs[q] < idx)) ? 1 : 0;
        }
        if (rk < K_NB) {
            float wgt = 1.f / (dv + DELTA);
            cw = wgt;
            cwv = wgt * vals[idx];
        }
    }
    #pragma unroll
    for (int m = 1; m < 64; m <<= 1) {
        cw  += __shfl_xor(cw,  m, 64);
        cwv += __shfl_xor(cwv, m, 64);
    }
    if ((t & 63) == 0) { rs[t >> 6] = cw; rvs[t >> 6] = cwv; }
    __syncthreads();
    if (t == 0) {
        float sw = rs[0] + rs[1] + rs[2] + rs[3];
        float sv = rvs[0] + rvs[1] + rvs[2] + rvs[3];
        out_val[r] = sv / sw;
    }
}

// ---------- launch ----------
extern "C" void kernel_launch(void* const* d_in, const int* in_sizes, int n_in,
                              void* d_out, int out_size, void* d_ws, size_t ws_size,
                              hipStream_t stream)
{
    const float* x    = (const float*)d_in[0];
    const float* W1   = (const float*)d_in[1];
    const float* b1   = (const float*)d_in[2];
    const float* Wp   = (const float*)d_in[3];
    const float* bp   = (const float*)d_in[4];
    const float* keys = (const float*)d_in[5];
    const float* vals = (const float*)d_in[6];
    float* out = (float*)d_out;
    float* ws  = (float*)d_ws;

    // ws layout (float units)
    float*          ws_h  = ws;                               // 65536
    float*          hsq   = ws + 65536;                       // 1024
    float*          ksq   = ws + 66560;                       // 200704 (padded)
    float*          thr   = ws + 267264;                      // 1024
    unsigned short* a2    = (unsigned short*)(ws + 268288);   // 65536 floats
    int*            cnt2  = (int*)(ws + 333824);              // 65536
    unsigned*       ovcnt = (unsigned*)(ws + 399360);         // 1024
    const size_t basef = 400384;

    // tier A: sample 4096 / rank 24 / cap 32 -> cand 8 MB (overlaid by d_sample) + ov 2 MB
    // tier B: sample 2048 / rank 12 / cap 16 -> cand 4 MB + ov 2 MB
    int sample, rank, cap;
    size_t candf;
    const size_t ovf = (size_t)BROWS * OVCAP * 2;             // 524288 floats
    size_t needA = (basef + 2097152 + ovf) * 4ull;            // ~12.1 MB
    if (ws_size >= needA) { sample = 4096; rank = 24; cap = 32; candf = 2097152; }
    else                  { sample = 2048; rank = 12; cap = 16; candf = 1048576; }

    unsigned*       cand     = (unsigned*)(ws + basef);
    ull*            ov       = (ull*)(ws + basef + candf);
    unsigned short* d_sample = (unsigned short*)cand;          // overlay (dead before k_dist)

    k_mlp<<<BROWS, 64, 0, stream>>>(x, W1, b1, Wp, bp, out, ws_h, hsq, ovcnt, a2);
    k_ksq<<<NKEYS / 16, 256, 0, stream>>>(keys, ksq);
    dim3 gsd(sample / 128, 8);
    k_sdist<<<gsd, 256, 0, stream>>>(keys, a2, hsq, ksq, d_sample, sample);
    k_sel<<<BROWS / 4, 256, 0, stream>>>(d_sample, thr, sample, rank);
    dim3 gdist(XB, 8);
    k_dist<<<gdist, 256, 0, stream>>>(keys, a2, hsq, ksq, thr, cnt2, ovcnt, ov, cand, cap);
    k_merge<<<BROWS, 256, 0, stream>>>(cand, cnt2, ovcnt, ov, vals, keys, ws_h, hsq, ksq,
                                       out + OUT_VAL_OFF, cap);
}